// Round 9
// baseline (555.616 us; speedup 1.0000x reference)
//
#include <hip/hip_runtime.h>

// ---------------- degree ----------------
__global__ void deg_kernel(const int* __restrict__ dst, int* __restrict__ deg, int E) {
    int e = blockIdx.x * blockDim.x + threadIdx.x;
    if (e < E) atomicAdd(&deg[dst[e]], 1);
}

// ---------------- scan1 (+ fused dinv) ----------------
__global__ void scan1_kernel(const int* __restrict__ deg, int* __restrict__ rowstart,
                             int* __restrict__ blockSums, float* __restrict__ dinv, int n) {
    __shared__ int tmp[256];
    int t = threadIdx.x;
    int i = blockIdx.x * 256 + t;
    int v = (i < n) ? deg[i] : 0;
    if (i < n) dinv[i] = rsqrtf((float)(v + 1));  // +1 = self loop
    tmp[t] = v;
    __syncthreads();
#pragma unroll
    for (int off = 1; off < 256; off <<= 1) {
        int add = (t >= off) ? tmp[t - off] : 0;
        __syncthreads();
        tmp[t] += add;
        __syncthreads();
    }
    if (i < n) rowstart[i] = tmp[t] - v;
    if (t == 255) blockSums[blockIdx.x] = tmp[255];
}

__global__ void scan2_kernel(int* __restrict__ blockSums, int nb) {
    __shared__ int tmp[512];
    int t = threadIdx.x;
    int v = (t < nb) ? blockSums[t] : 0;
    tmp[t] = v;
    __syncthreads();
#pragma unroll
    for (int off = 1; off < 512; off <<= 1) {
        int add = (t >= off) ? tmp[t - off] : 0;
        __syncthreads();
        tmp[t] += add;
        __syncthreads();
    }
    if (t < nb) blockSums[t] = tmp[t] - v;
}

__global__ void scan3_kernel(int* __restrict__ rowstart, const int* __restrict__ blockSums,
                             int* __restrict__ cursor, int n) {
    int i = blockIdx.x * blockDim.x + threadIdx.x;
    if (i < n) {
        int r = rowstart[i] + blockSums[i >> 8];
        rowstart[i] = r;
        cursor[i] = r;
    }
}

// ---------------- fused: counting-sort (4B payload)  |  GEMM1 ----------------
__global__ __launch_bounds__(256) void sort_gemm1_kernel(
        const int* __restrict__ src, const int* __restrict__ dst,
        int* __restrict__ cursor, int* __restrict__ srcSorted, int E,
        const float* __restrict__ x, const float* __restrict__ W,
        float* __restrict__ h, int n) {
    __shared__ float xs[64][128];
    int bid = blockIdx.x;
    int t = threadIdx.x;
    if (bid % 5 == 0) {
        // ---- GEMM1: 64-node x 128-col tile, reg tile 8x4, k-step 4 ----
        int node0 = (bid / 5) * 64;
#pragma unroll
        for (int i = 0; i < 8; i++) {
            int fi = t + 256 * i;
            int row = fi >> 5, cv = fi & 31;
            float4 v = make_float4(0.f, 0.f, 0.f, 0.f);
            if (node0 + row < n) v = ((const float4*)x)[(size_t)(node0 + row) * 32 + cv];
            ((float4*)(&xs[0][0]))[fi] = v;
        }
        __syncthreads();

        int tx = t & 31, ty = t >> 5;
        int c0 = tx * 4;
        float acc[8][4];
#pragma unroll
        for (int i = 0; i < 8; i++)
#pragma unroll
            for (int j = 0; j < 4; j++) acc[i][j] = 0.f;

        for (int k = 0; k < 128; k += 4) {
            float4 w0 = *(const float4*)(W + (k + 0) * 128 + c0);
            float4 w1 = *(const float4*)(W + (k + 1) * 128 + c0);
            float4 w2 = *(const float4*)(W + (k + 2) * 128 + c0);
            float4 w3 = *(const float4*)(W + (k + 3) * 128 + c0);
#pragma unroll
            for (int i = 0; i < 8; i++) {
                float4 xv = *(const float4*)(&xs[ty + 8 * i][k]);
                acc[i][0] += xv.x * w0.x + xv.y * w1.x + xv.z * w2.x + xv.w * w3.x;
                acc[i][1] += xv.x * w0.y + xv.y * w1.y + xv.z * w2.y + xv.w * w3.y;
                acc[i][2] += xv.x * w0.z + xv.y * w1.z + xv.z * w2.z + xv.w * w3.z;
                acc[i][3] += xv.x * w0.w + xv.y * w1.w + xv.z * w2.w + xv.w * w3.w;
            }
        }
#pragma unroll
        for (int i = 0; i < 8; i++) {
            int node = node0 + ty + 8 * i;
            if (node < n)
                *(float4*)(h + (size_t)node * 128 + c0) =
                    make_float4(acc[i][0], acc[i][1], acc[i][2], acc[i][3]);
        }
    } else {
        // ---- counting sort: one edge per thread, 4B payload ----
        int sb = (bid / 5) * 4 + (bid % 5) - 1;
        int e = sb * 256 + t;
        if (e < E) {
            int s = src[e], d = dst[e];
            int pos = atomicAdd(&cursor[d], 1);
            srcSorted[pos] = s;
        }
    }
}

// ---------------- gather1: h2 = relu(agg(h1) + b1), column-split by XCD parity ----------------
// blockIdx&1 selects 64-col half (even->cols 0..63 on XCDs 0/2/4/6, odd->64..127),
// halving each XCD's L2 working set of h1. 1 wave per (node, half); scalar 4B/lane.
__global__ __launch_bounds__(256) void gather1_kernel(
        const int* __restrict__ srcS, const int* __restrict__ rowstart,
        const int* __restrict__ deg, const float* __restrict__ dinv,
        const float* __restrict__ h1, const float* __restrict__ b1,
        float* __restrict__ h2, int n) {
    int t = threadIdx.x;
    int w = t >> 6, lane = t & 63;
    int half = blockIdx.x & 1;
    int g = (blockIdx.x >> 1) * 4 + w;
    if (g >= n) return;
    int col = (half << 6) + lane;

    float dg = dinv[g];
    float acc = dg * dg * h1[(size_t)g * 128 + col];
    int beg = rowstart[g], end = beg + deg[g];
    int e = beg;
    for (; e + 8 <= end; e += 8) {
        int s0 = srcS[e+0], s1 = srcS[e+1], s2 = srcS[e+2], s3 = srcS[e+3];
        int s4 = srcS[e+4], s5 = srcS[e+5], s6 = srcS[e+6], s7 = srcS[e+7];
        float u0 = h1[(size_t)s0 * 128 + col];
        float u1 = h1[(size_t)s1 * 128 + col];
        float u2 = h1[(size_t)s2 * 128 + col];
        float u3 = h1[(size_t)s3 * 128 + col];
        float u4 = h1[(size_t)s4 * 128 + col];
        float u5 = h1[(size_t)s5 * 128 + col];
        float u6 = h1[(size_t)s6 * 128 + col];
        float u7 = h1[(size_t)s7 * 128 + col];
        acc += dinv[s0] * dg * u0 + dinv[s1] * dg * u1 +
               dinv[s2] * dg * u2 + dinv[s3] * dg * u3 +
               dinv[s4] * dg * u4 + dinv[s5] * dg * u5 +
               dinv[s6] * dg * u6 + dinv[s7] * dg * u7;
    }
    for (; e < end; e++) {
        int s = srcS[e];
        acc += dinv[s] * dg * h1[(size_t)s * 128 + col];
    }
    h2[(size_t)g * 128 + col] = fmaxf(acc + b1[col], 0.f);
}

// ---------------- GEMM2: h3[N,64] = h2[N,128] @ W2[128,64] ----------------
// k-step 1, scalar LDS reads (VGPR ~32, high occupancy — proven R4 shape)
__global__ __launch_bounds__(256) void gemm_nk64(const float* __restrict__ x,
                                                 const float* __restrict__ W,
                                                 float* __restrict__ h, int n) {
    __shared__ float xs[32][128];
    int t = threadIdx.x;
    int node0 = blockIdx.x * 32;
#pragma unroll
    for (int i = 0; i < 4; i++) {
        int fi = t + 256 * i;
        int row = fi >> 5, cv = fi & 31;
        float4 v = make_float4(0.f, 0.f, 0.f, 0.f);
        if (node0 + row < n) v = ((const float4*)x)[(size_t)(node0 + row) * 32 + cv];
        ((float4*)(&xs[0][0]))[fi] = v;
    }
    __syncthreads();

    int tx = t & 15, ty = t >> 4;
    int c0 = tx * 4;
    float acc[2][4];
#pragma unroll
    for (int i = 0; i < 2; i++)
#pragma unroll
        for (int j = 0; j < 4; j++) acc[i][j] = 0.f;

    for (int k = 0; k < 128; k++) {
        float4 w = *(const float4*)(W + k * 64 + c0);
#pragma unroll
        for (int i = 0; i < 2; i++) {
            float xval = xs[ty + 16 * i][k];
            acc[i][0] += xval * w.x;
            acc[i][1] += xval * w.y;
            acc[i][2] += xval * w.z;
            acc[i][3] += xval * w.w;
        }
    }
#pragma unroll
    for (int i = 0; i < 2; i++) {
        int node = node0 + ty + 16 * i;
        if (node < n)
            *(float4*)(h + (size_t)node * 64 + c0) =
                make_float4(acc[i][0], acc[i][1], acc[i][2], acc[i][3]);
    }
}

// ---------------- gather2: out = agg(h3) + b2, column-split by XCD parity ----------------
// blockIdx&1 selects 32-col half (= one 128B line per row). 2 nodes per wave.
__global__ __launch_bounds__(256) void gather2_kernel(
        const int* __restrict__ srcS, const int* __restrict__ rowstart,
        const int* __restrict__ deg, const float* __restrict__ dinv,
        const float* __restrict__ h3, const float* __restrict__ b2,
        float* __restrict__ out, int n) {
    int t = threadIdx.x;
    int w = t >> 6, lane = t & 63;
    int half = blockIdx.x & 1;
    int g = (blockIdx.x >> 1) * 8 + w * 2 + (lane >> 5);
    if (g >= n) return;
    int col = (half << 5) + (lane & 31);

    float dg = dinv[g];
    float acc = dg * dg * h3[(size_t)g * 64 + col];
    int beg = rowstart[g], end = beg + deg[g];
    int e = beg;
    for (; e + 8 <= end; e += 8) {
        int s0 = srcS[e+0], s1 = srcS[e+1], s2 = srcS[e+2], s3 = srcS[e+3];
        int s4 = srcS[e+4], s5 = srcS[e+5], s6 = srcS[e+6], s7 = srcS[e+7];
        float u0 = h3[(size_t)s0 * 64 + col];
        float u1 = h3[(size_t)s1 * 64 + col];
        float u2 = h3[(size_t)s2 * 64 + col];
        float u3 = h3[(size_t)s3 * 64 + col];
        float u4 = h3[(size_t)s4 * 64 + col];
        float u5 = h3[(size_t)s5 * 64 + col];
        float u6 = h3[(size_t)s6 * 64 + col];
        float u7 = h3[(size_t)s7 * 64 + col];
        acc += dinv[s0] * dg * u0 + dinv[s1] * dg * u1 +
               dinv[s2] * dg * u2 + dinv[s3] * dg * u3 +
               dinv[s4] * dg * u4 + dinv[s5] * dg * u5 +
               dinv[s6] * dg * u6 + dinv[s7] * dg * u7;
    }
    for (; e < end; e++) {
        int s = srcS[e];
        acc += dinv[s] * dg * h3[(size_t)s * 64 + col];
    }
    out[(size_t)g * 64 + col] = acc + b2[col];
}

extern "C" void kernel_launch(void* const* d_in, const int* in_sizes, int n_in,
                              void* d_out, int out_size, void* d_ws, size_t ws_size,
                              hipStream_t stream) {
    const float* x  = (const float*)d_in[0];
    const int*   ei = (const int*)d_in[1];
    const float* W1 = (const float*)d_in[2];
    const float* b1 = (const float*)d_in[3];
    const float* W2 = (const float*)d_in[4];
    const float* b2 = (const float*)d_in[5];
    float* out = (float*)d_out;

    const int n = in_sizes[0] / 128;   // 100000
    const int E = in_sizes[1] / 2;     // 1600000
    const int* src = ei;
    const int* dst = ei + E;
    const int nb = (n + 255) / 256;

    char* ws = (char*)d_ws;
    size_t off = 0;
    auto carve = [&](size_t bytes) -> char* {
        char* p = ws + off;
        off += (bytes + 255) & ~(size_t)255;
        return p;
    };
    int*   deg       = (int*)carve((size_t)n * 4);
    float* dinv      = (float*)carve((size_t)n * 4);
    int*   rowstart  = (int*)carve((size_t)n * 4);
    int*   cursor    = (int*)carve((size_t)n * 4);
    int*   blockSums = (int*)carve((size_t)nb * 4);
    int*   srcSorted = (int*)carve((size_t)E * 4);
    float* bufA      = (float*)carve((size_t)n * 128 * 4);  // h1, then h3
    float* bufB      = (float*)carve((size_t)n * 128 * 4);  // h2

    hipMemsetAsync(deg, 0, (size_t)n * 4, stream);

    deg_kernel<<<(E + 255) / 256, 256, 0, stream>>>(dst, deg, E);
    scan1_kernel<<<nb, 256, 0, stream>>>(deg, rowstart, blockSums, dinv, n);
    scan2_kernel<<<1, 512, 0, stream>>>(blockSums, nb);
    scan3_kernel<<<(n + 255) / 256, 256, 0, stream>>>(rowstart, blockSums, cursor, n);

    // fused sort | gemm1 (independent work, interleaved 1:4)
    int gemmBlocks = (n + 63) / 64;
    int sortBlocks = (E + 255) / 256;
    int G1 = ((sortBlocks + 3) / 4) * 5;
    int G2 = gemmBlocks * 5;
    int G = (G1 > G2) ? G1 : G2;
    sort_gemm1_kernel<<<G, 256, 0, stream>>>(src, dst, cursor, srcSorted, E,
                                             x, W1, bufA, n);

    // layer 1 aggregation: h2 = relu(agg(h1) + b1)  [2 blocks per 4-node group: col halves]
    gather1_kernel<<<2 * ((n + 3) / 4), 256, 0, stream>>>(srcSorted, rowstart, deg, dinv,
                                                          bufA, b1, bufB, n);

    // layer 2: h3 = h2@W2 (reuse bufA) ; out = agg(h3) + b2  [col halves]
    gemm_nk64<<<(n + 31) / 32, 256, 0, stream>>>(bufB, W2, bufA, n);
    gather2_kernel<<<2 * ((n + 7) / 8), 256, 0, stream>>>(srcSorted, rowstart, deg, dinv,
                                                          bufA, b2, out, n);
}